// Round 3
// baseline (665.272 us; speedup 1.0000x reference)
//
#include <hip/hip_runtime.h>
#include <stdint.h>

// DiffAttention: O[n,h,d] = sum_l sigmoid(q_n.k_l) v_l / sum_l sigmoid(q_n.k_l)
// N=L=4096, H=8, M=D=64, fp32 in/out, bf16 MFMA compute.
//
// R3: three kernels.
//  1) prepass: K -> bf16 [h][l][m], V -> bf16 tile-major transposed
//     [h][t][d][l'], both with XOR-swizzled 16B chunks per 128B row
//     (phys = logical ^ (row&7)) so main-kernel frag reads are conflict-free
//     without padding (global_load_lds requires an unpadded contiguous image).
//  2) partial: split-L flash loop, staging via global_load_lds_dwordx4 only,
//     8 blocks/CU target. Writes raw numerator + Z per split.
//  3) combine: sum splits, divide.

typedef __bf16 bf16x8 __attribute__((ext_vector_type(8)));
typedef __bf16 bf16x2 __attribute__((ext_vector_type(2)));
typedef float  f32x2  __attribute__((ext_vector_type(2)));
typedef float  f32x16 __attribute__((ext_vector_type(16)));

constexpr int NH = 8, MD = 64, NL = 4096, NN = 4096;
constexpr size_t ONUM_ELEMS = (size_t)NN * NH * MD;  // per split
constexpr size_t Z_ELEMS    = (size_t)NN * NH;       // per split
constexpr size_t KB_ELEMS   = (size_t)NH * NL * MD;  // bf16
constexpr size_t VTB_ELEMS  = (size_t)NH * NL * MD;  // bf16

__device__ __forceinline__ unsigned packbf2(float a, float b) {
  bf16x2 t = __builtin_convertvector((f32x2){a, b}, bf16x2);
  return __builtin_bit_cast(unsigned, t);
}

__device__ __forceinline__ void glds16(const void* g, void* l) {
  __builtin_amdgcn_global_load_lds(
      (const __attribute__((address_space(1))) unsigned int*)g,
      (__attribute__((address_space(3))) unsigned int*)l, 16, 0, 0);
}

// ---------------- prepass: one block per (h, l-tile) ----------------
__global__ __launch_bounds__(256) void diffattn_prepass(
    const float* __restrict__ Kg, const float* __restrict__ Vg,
    unsigned short* __restrict__ Kb, unsigned short* __restrict__ Vtb) {
  __shared__ __attribute__((aligned(16))) unsigned short Vt_lds[64 * 64];
  const int tid = threadIdx.x;
  const int h = blockIdx.x & 7;
  const int t = blockIdx.x >> 3;

  // ---- K: [l][h][m] fp32 -> [h][l][m] bf16, 16B chunks swizzled by l&7
#pragma unroll
  for (int e = 0; e < 2; ++e) {
    const int g = tid * 2 + e;
    const int l = g >> 3, c = g & 7;
    const float* kp = Kg + (((size_t)(t * 64 + l) * NH + h) * MD) + c * 8;
    const float4 a = *(const float4*)kp;
    const float4 b = *(const float4*)(kp + 4);
    unsigned out[4] = {packbf2(a.x, a.y), packbf2(a.z, a.w),
                       packbf2(b.x, b.y), packbf2(b.z, b.w)};
    unsigned short* dst =
        Kb + ((size_t)h * NL + t * 64 + l) * MD + ((c ^ (l & 7)) * 8);
    *(uint4*)dst = *(const uint4*)out;
  }

  // ---- V: [l][h][d] fp32 -> LDS transpose -> [h][t][d][l'] bf16,
  //      16B chunks (8 l' each) swizzled by d&7
  {
    const int lr = tid & 63, dbase = (tid >> 6) * 16;
    const float* vp = Vg + (((size_t)(t * 64 + lr) * NH + h) * MD) + dbase;
#pragma unroll
    for (int i = 0; i < 4; ++i) {
      const float4 v = *(const float4*)(vp + i * 4);
      const int d0 = dbase + i * 4;
      Vt_lds[(d0 + 0) * 64 + lr] = __builtin_bit_cast(unsigned short, (__bf16)v.x);
      Vt_lds[(d0 + 1) * 64 + lr] = __builtin_bit_cast(unsigned short, (__bf16)v.y);
      Vt_lds[(d0 + 2) * 64 + lr] = __builtin_bit_cast(unsigned short, (__bf16)v.z);
      Vt_lds[(d0 + 3) * 64 + lr] = __builtin_bit_cast(unsigned short, (__bf16)v.w);
    }
  }
  __syncthreads();
#pragma unroll
  for (int e = 0; e < 2; ++e) {
    const int g = tid * 2 + e;
    const int d = g >> 3, cl = g & 7;
    const uint4 chunk = *(const uint4*)&Vt_lds[d * 64 + cl * 8];
    unsigned short* dst = Vtb + ((size_t)(h * 64 + t) * 64 + d) * 64 +
                          ((cl ^ (d & 7)) * 8);
    *(uint4*)dst = chunk;
  }
}

// ---------------- partial ----------------
__global__ __launch_bounds__(256, 8) void diffattn_partial(
    const float* __restrict__ Qg, const unsigned short* __restrict__ Kb,
    const unsigned short* __restrict__ Vtb, float* __restrict__ Onum,
    float* __restrict__ Zp, int nsplit, int lLen) {
  __shared__ __attribute__((aligned(16))) unsigned short Ksh[64 * 64];
  __shared__ __attribute__((aligned(16))) unsigned short Vtsh[64 * 64];
  __shared__ float Zsh[4][32];

  const int tid  = threadIdx.x;
  const int w    = tid >> 6;
  const int lane = tid & 63;
  const int col  = lane & 31;
  const int hi   = lane >> 5;

  const int h     = blockIdx.x & 7;
  const int tmp   = blockIdx.x >> 3;
  const int split = tmp % nsplit;
  const int n0    = (tmp / nsplit) * 128;
  const int lBeg  = split * lLen;

  // Q fragments (B operand), prescaled by -log2e: sigmoid = rcp(1+exp2(d1)).
  bf16x8 qf[4];
  {
    const float* qp = Qg + ((size_t)(n0 + w * 32 + col) * NH + h) * MD;
    const float c = -1.4426950408889634f;
#pragma unroll
    for (int kc = 0; kc < 4; ++kc) {
      const float4 x = *(const float4*)(qp + kc * 16 + hi * 8);
      const float4 y = *(const float4*)(qp + kc * 16 + hi * 8 + 4);
      bf16x8 f;
      f[0] = (__bf16)(c * x.x); f[1] = (__bf16)(c * x.y);
      f[2] = (__bf16)(c * x.z); f[3] = (__bf16)(c * x.w);
      f[4] = (__bf16)(c * y.x); f[5] = (__bf16)(c * y.y);
      f[6] = (__bf16)(c * y.z); f[7] = (__bf16)(c * y.w);
      qf[kc] = f;
    }
  }

  f32x16 oacc[2];
#pragma unroll
  for (int i = 0; i < 16; ++i) { oacc[0][i] = 0.f; oacc[1][i] = 0.f; }
  float zacc = 0.f;

  const char* kgh = (const char*)(Kb + (size_t)h * NL * MD);
  const char* vgh = (const char*)(Vtb + (size_t)h * NL * MD);

  for (int l0 = lBeg; l0 < lBeg + lLen; l0 += 64) {
    const char* kgb = kgh + (size_t)l0 * 128;   // 64 l x 128B rows, contiguous
    const char* vgb = vgh + (size_t)l0 * 128;   // tile-major: t*8KB
    __syncthreads();  // previous tile fully consumed by all waves
    {
      const int o = w * 2048 + lane * 16;
      glds16(kgb + o,        (char*)Ksh  + w * 2048);
      glds16(kgb + o + 1024, (char*)Ksh  + w * 2048 + 1024);
      glds16(vgb + o,        (char*)Vtsh + w * 2048);
      glds16(vgb + o + 1024, (char*)Vtsh + w * 2048 + 1024);
    }
    __syncthreads();  // compiler emits vmcnt(0) drain before barrier

    // ---- scores^T: D1[lh] (32 l x 32 m) = K(32l x 64k) x Qscaled(64k x 32m)
    f32x16 d1[2];
#pragma unroll
    for (int i = 0; i < 16; ++i) { d1[0][i] = 0.f; d1[1][i] = 0.f; }
#pragma unroll
    for (int lh = 0; lh < 2; ++lh) {
      const int rowK = lh * 32 + col;
      const char* kp = (const char*)Ksh + rowK * 128;
      const int sw = rowK & 7;
#pragma unroll
      for (int kc = 0; kc < 4; ++kc) {
        const bf16x8 kf = *(const bf16x8*)(kp + (((kc << 1) | hi) ^ sw) * 16);
        d1[lh] = __builtin_amdgcn_mfma_f32_32x32x16_bf16(kf, qf[kc], d1[lh], 0, 0, 0);
      }
    }

    // ---- sigmoid + Z accumulate + pack pairs (consecutive l_local) to bf16
    unsigned pk[2][8];
#pragma unroll
    for (int lh = 0; lh < 2; ++lh) {
      float s[16];
#pragma unroll
      for (int r = 0; r < 16; ++r) {
        const float e = __builtin_amdgcn_exp2f(d1[lh][r]);
        s[r] = __builtin_amdgcn_rcpf(1.0f + e);
        zacc += s[r];
      }
#pragma unroll
      for (int p = 0; p < 8; ++p) pk[lh][p] = packbf2(s[2 * p], s[2 * p + 1]);
    }

    // ---- O += P(32m x 64l) x V(64l x 64d); P A-frag built via lane^32 swap
#pragma unroll
    for (int kc2 = 0; kc2 < 4; ++kc2) {
      const int lh = kc2 >> 1, s4 = (kc2 & 1) * 4;
      const unsigned send0 = hi ? pk[lh][s4 + 0] : pk[lh][s4 + 2];
      const unsigned send1 = hi ? pk[lh][s4 + 1] : pk[lh][s4 + 3];
      const unsigned recv0 = (unsigned)__shfl_xor((int)send0, 32, 64);
      const unsigned recv1 = (unsigned)__shfl_xor((int)send1, 32, 64);
      union { unsigned u[4]; bf16x8 v; } pf;
      if (hi == 0) {
        pf.u[0] = pk[lh][s4 + 0]; pf.u[1] = pk[lh][s4 + 1];
        pf.u[2] = recv0;          pf.u[3] = recv1;
      } else {
        pf.u[0] = recv0;          pf.u[1] = recv1;
        pf.u[2] = pk[lh][s4 + 2]; pf.u[3] = pk[lh][s4 + 3];
      }
#pragma unroll
      for (int ds = 0; ds < 2; ++ds) {
        const int rowV = ds * 32 + col;
        const bf16x8 vf = *(const bf16x8*)((const char*)Vtsh + rowV * 128 +
                                           (((kc2 << 1) | hi) ^ (rowV & 7)) * 16);
        oacc[ds] = __builtin_amdgcn_mfma_f32_32x32x16_bf16(pf.v, vf, oacc[ds], 0, 0, 0);
      }
    }
  }

  // ---- epilogue: store raw numerator + Z partial (no divide here)
  const float zrow = zacc + __shfl_xor(zacc, 32, 64);
  if (hi == 0) Zp[(size_t)split * Z_ELEMS + (size_t)(n0 + w * 32 + col) * NH + h] = zrow;

  float* onum = Onum + (size_t)split * ONUM_ELEMS;
#pragma unroll
  for (int ds = 0; ds < 2; ++ds) {
    const int d = ds * 32 + col;
#pragma unroll
    for (int r = 0; r < 16; ++r) {
      const int row = (r & 3) + 8 * (r >> 2) + 4 * hi;
      onum[((size_t)(n0 + w * 32 + row) * NH + h) * MD + d] = oacc[ds][r];
    }
  }
}

// ---------------- combine ----------------
__global__ __launch_bounds__(256) void diffattn_combine(
    const float* __restrict__ Onum, const float* __restrict__ Zp,
    float* __restrict__ Og, int nsplit) {
  const int idx = blockIdx.x * 256 + threadIdx.x;  // one float4 of output
  if (idx >= (int)(ONUM_ELEMS / 4)) return;
  const int nh = idx >> 4;
  const int d4 = (idx & 15) * 4;
  float z = 0.f;
  float4 o = make_float4(0.f, 0.f, 0.f, 0.f);
  for (int s = 0; s < nsplit; ++s) {
    z += Zp[(size_t)s * Z_ELEMS + nh];
    const float4 t = *(const float4*)(Onum + (size_t)s * ONUM_ELEMS +
                                      (size_t)nh * MD + d4);
    o.x += t.x; o.y += t.y; o.z += t.z; o.w += t.w;
  }
  const float zi = __builtin_amdgcn_rcpf(z);
  float4 r = make_float4(o.x * zi, o.y * zi, o.z * zi, o.w * zi);
  *(float4*)(Og + (size_t)nh * MD + d4) = r;
}

extern "C" void kernel_launch(void* const* d_in, const int* in_sizes, int n_in,
                              void* d_out, int out_size, void* d_ws, size_t ws_size,
                              hipStream_t stream) {
  const float* Q = (const float*)d_in[0];
  const float* K = (const float*)d_in[1];
  const float* V = (const float*)d_in[2];
  float* O = (float*)d_out;

  const size_t conv_bytes = (KB_ELEMS + VTB_ELEMS) * sizeof(unsigned short);
  int nsplit = 8;
  while (nsplit > 1 &&
         (size_t)nsplit * (ONUM_ELEMS + Z_ELEMS) * sizeof(float) + conv_bytes >
             ws_size)
    nsplit >>= 1;

  float* Onum = (float*)d_ws;
  float* Zp   = Onum + (size_t)nsplit * ONUM_ELEMS;
  unsigned short* Kbb = (unsigned short*)(Zp + (size_t)nsplit * Z_ELEMS);
  unsigned short* Vtb = Kbb + KB_ELEMS;

  const int lLen = NL / nsplit;
  diffattn_prepass<<<dim3(8 * (NL / 64)), dim3(256), 0, stream>>>(K, V, Kbb, Vtb);
  diffattn_partial<<<dim3(8 * 32 * nsplit), dim3(256), 0, stream>>>(
      Q, Kbb, Vtb, Onum, Zp, nsplit, lLen);
  diffattn_combine<<<dim3((ONUM_ELEMS / 4 + 255) / 256), dim3(256), 0, stream>>>(
      Onum, Zp, O, nsplit);
}

// Round 4
// 131.592 us; speedup vs baseline: 5.0556x; 5.0556x over previous
//
#include <hip/hip_runtime.h>
#include <stdint.h>

// DiffAttention: O[n,h,d] = sum_l sigmoid(q_n.k_l) v_l / sum_l sigmoid(q_n.k_l)
// N=L=4096, H=8, M=D=64, fp32 in/out, bf16 MFMA compute.
//
// R4 = R3 structure with the spill fixed:
//  - __launch_bounds__(256,4): VGPR cap 128. (256,8) forced 32 VGPRs ->
//    catastrophic scratch spill (966MB FETCH / 1.8GB WRITE per dispatch).
//  - nsplit=4: 1024 blocks = exactly 4 blocks/CU, no residency tail,
//    combine traffic halved vs nsplit=8.
//  1) prepass: K -> bf16 [h][l][m], V -> bf16 tile-major transposed
//     [h][t][d][l'], XOR-swizzled 16B chunks per 128B row (phys = log ^ (row&7))
//     -> conflict-free frag reads without padding (glds needs contiguous image).
//  2) partial: split-L flash loop, staging via global_load_lds_dwordx4 only.
//  3) combine: sum splits, divide.

typedef __bf16 bf16x8 __attribute__((ext_vector_type(8)));
typedef __bf16 bf16x2 __attribute__((ext_vector_type(2)));
typedef float  f32x2  __attribute__((ext_vector_type(2)));
typedef float  f32x16 __attribute__((ext_vector_type(16)));

constexpr int NH = 8, MD = 64, NL = 4096, NN = 4096;
constexpr size_t ONUM_ELEMS = (size_t)NN * NH * MD;  // per split
constexpr size_t Z_ELEMS    = (size_t)NN * NH;       // per split
constexpr size_t KB_ELEMS   = (size_t)NH * NL * MD;  // bf16
constexpr size_t VTB_ELEMS  = (size_t)NH * NL * MD;  // bf16

__device__ __forceinline__ unsigned packbf2(float a, float b) {
  bf16x2 t = __builtin_convertvector((f32x2){a, b}, bf16x2);
  return __builtin_bit_cast(unsigned, t);
}

__device__ __forceinline__ void glds16(const void* g, void* l) {
  __builtin_amdgcn_global_load_lds(
      (const __attribute__((address_space(1))) unsigned int*)g,
      (__attribute__((address_space(3))) unsigned int*)l, 16, 0, 0);
}

// ---------------- prepass: one block per (h, l-tile) ----------------
__global__ __launch_bounds__(256) void diffattn_prepass(
    const float* __restrict__ Kg, const float* __restrict__ Vg,
    unsigned short* __restrict__ Kb, unsigned short* __restrict__ Vtb) {
  __shared__ __attribute__((aligned(16))) unsigned short Vt_lds[64 * 64];
  const int tid = threadIdx.x;
  const int h = blockIdx.x & 7;
  const int t = blockIdx.x >> 3;

  // ---- K: [l][h][m] fp32 -> [h][l][m] bf16, 16B chunks swizzled by l&7
#pragma unroll
  for (int e = 0; e < 2; ++e) {
    const int g = tid * 2 + e;
    const int l = g >> 3, c = g & 7;
    const float* kp = Kg + (((size_t)(t * 64 + l) * NH + h) * MD) + c * 8;
    const float4 a = *(const float4*)kp;
    const float4 b = *(const float4*)(kp + 4);
    unsigned out[4] = {packbf2(a.x, a.y), packbf2(a.z, a.w),
                       packbf2(b.x, b.y), packbf2(b.z, b.w)};
    unsigned short* dst =
        Kb + ((size_t)h * NL + t * 64 + l) * MD + ((c ^ (l & 7)) * 8);
    *(uint4*)dst = *(const uint4*)out;
  }

  // ---- V: [l][h][d] fp32 -> LDS transpose -> [h][t][d][l'] bf16,
  //      16B chunks (8 l' each) swizzled by d&7
  {
    const int lr = tid & 63, dbase = (tid >> 6) * 16;
    const float* vp = Vg + (((size_t)(t * 64 + lr) * NH + h) * MD) + dbase;
#pragma unroll
    for (int i = 0; i < 4; ++i) {
      const float4 v = *(const float4*)(vp + i * 4);
      const int d0 = dbase + i * 4;
      Vt_lds[(d0 + 0) * 64 + lr] = __builtin_bit_cast(unsigned short, (__bf16)v.x);
      Vt_lds[(d0 + 1) * 64 + lr] = __builtin_bit_cast(unsigned short, (__bf16)v.y);
      Vt_lds[(d0 + 2) * 64 + lr] = __builtin_bit_cast(unsigned short, (__bf16)v.z);
      Vt_lds[(d0 + 3) * 64 + lr] = __builtin_bit_cast(unsigned short, (__bf16)v.w);
    }
  }
  __syncthreads();
#pragma unroll
  for (int e = 0; e < 2; ++e) {
    const int g = tid * 2 + e;
    const int d = g >> 3, cl = g & 7;
    const uint4 chunk = *(const uint4*)&Vt_lds[d * 64 + cl * 8];
    unsigned short* dst = Vtb + ((size_t)(h * 64 + t) * 64 + d) * 64 +
                          ((cl ^ (d & 7)) * 8);
    *(uint4*)dst = chunk;
  }
}

// ---------------- partial ----------------
__global__ __launch_bounds__(256, 4) void diffattn_partial(
    const float* __restrict__ Qg, const unsigned short* __restrict__ Kb,
    const unsigned short* __restrict__ Vtb, float* __restrict__ Onum,
    float* __restrict__ Zp, int nsplit, int lLen) {
  __shared__ __attribute__((aligned(16))) unsigned short Ksh[64 * 64];
  __shared__ __attribute__((aligned(16))) unsigned short Vtsh[64 * 64];

  const int tid  = threadIdx.x;
  const int w    = tid >> 6;
  const int lane = tid & 63;
  const int col  = lane & 31;
  const int hi   = lane >> 5;

  const int h     = blockIdx.x & 7;
  const int tmp   = blockIdx.x >> 3;
  const int split = tmp % nsplit;
  const int n0    = (tmp / nsplit) * 128;
  const int lBeg  = split * lLen;

  // Q fragments (B operand), prescaled by -log2e: sigmoid = rcp(1+exp2(d1)).
  bf16x8 qf[4];
  {
    const float* qp = Qg + ((size_t)(n0 + w * 32 + col) * NH + h) * MD;
    const float c = -1.4426950408889634f;
#pragma unroll
    for (int kc = 0; kc < 4; ++kc) {
      const float4 x = *(const float4*)(qp + kc * 16 + hi * 8);
      const float4 y = *(const float4*)(qp + kc * 16 + hi * 8 + 4);
      bf16x8 f;
      f[0] = (__bf16)(c * x.x); f[1] = (__bf16)(c * x.y);
      f[2] = (__bf16)(c * x.z); f[3] = (__bf16)(c * x.w);
      f[4] = (__bf16)(c * y.x); f[5] = (__bf16)(c * y.y);
      f[6] = (__bf16)(c * y.z); f[7] = (__bf16)(c * y.w);
      qf[kc] = f;
    }
  }

  f32x16 oacc[2];
#pragma unroll
  for (int i = 0; i < 16; ++i) { oacc[0][i] = 0.f; oacc[1][i] = 0.f; }
  float zacc = 0.f;

  const char* kgh = (const char*)(Kb + (size_t)h * NL * MD);
  const char* vgh = (const char*)(Vtb + (size_t)h * NL * MD);

  for (int l0 = lBeg; l0 < lBeg + lLen; l0 += 64) {
    const char* kgb = kgh + (size_t)l0 * 128;   // 64 l x 128B rows, contiguous
    const char* vgb = vgh + (size_t)l0 * 128;   // tile-major: t*8KB
    __syncthreads();  // previous tile fully consumed by all waves
    {
      const int o = w * 2048 + lane * 16;
      glds16(kgb + o,        (char*)Ksh  + w * 2048);
      glds16(kgb + o + 1024, (char*)Ksh  + w * 2048 + 1024);
      glds16(vgb + o,        (char*)Vtsh + w * 2048);
      glds16(vgb + o + 1024, (char*)Vtsh + w * 2048 + 1024);
    }
    __syncthreads();  // vmcnt(0) drain before barrier

    // ---- scores^T: D1[lh] (32 l x 32 m) = K(32l x 64k) x Qscaled(64k x 32m)
    f32x16 d1[2];
#pragma unroll
    for (int i = 0; i < 16; ++i) { d1[0][i] = 0.f; d1[1][i] = 0.f; }
#pragma unroll
    for (int lh = 0; lh < 2; ++lh) {
      const int rowK = lh * 32 + col;
      const char* kp = (const char*)Ksh + rowK * 128;
      const int sw = rowK & 7;
#pragma unroll
      for (int kc = 0; kc < 4; ++kc) {
        const bf16x8 kf = *(const bf16x8*)(kp + (((kc << 1) | hi) ^ sw) * 16);
        d1[lh] = __builtin_amdgcn_mfma_f32_32x32x16_bf16(kf, qf[kc], d1[lh], 0, 0, 0);
      }
    }

    // ---- sigmoid + Z accumulate + pack pairs (consecutive l_local) to bf16
    unsigned pk[2][8];
#pragma unroll
    for (int lh = 0; lh < 2; ++lh) {
      float s[16];
#pragma unroll
      for (int r = 0; r < 16; ++r) {
        const float e = __builtin_amdgcn_exp2f(d1[lh][r]);
        s[r] = __builtin_amdgcn_rcpf(1.0f + e);
        zacc += s[r];
      }
#pragma unroll
      for (int p = 0; p < 8; ++p) pk[lh][p] = packbf2(s[2 * p], s[2 * p + 1]);
    }

    // ---- O += P(32m x 64l) x V(64l x 64d); P A-frag built via lane^32 swap
#pragma unroll
    for (int kc2 = 0; kc2 < 4; ++kc2) {
      const int lh = kc2 >> 1, s4 = (kc2 & 1) * 4;
      const unsigned send0 = hi ? pk[lh][s4 + 0] : pk[lh][s4 + 2];
      const unsigned send1 = hi ? pk[lh][s4 + 1] : pk[lh][s4 + 3];
      const unsigned recv0 = (unsigned)__shfl_xor((int)send0, 32, 64);
      const unsigned recv1 = (unsigned)__shfl_xor((int)send1, 32, 64);
      union { unsigned u[4]; bf16x8 v; } pf;
      if (hi == 0) {
        pf.u[0] = pk[lh][s4 + 0]; pf.u[1] = pk[lh][s4 + 1];
        pf.u[2] = recv0;          pf.u[3] = recv1;
      } else {
        pf.u[0] = recv0;          pf.u[1] = recv1;
        pf.u[2] = pk[lh][s4 + 2]; pf.u[3] = pk[lh][s4 + 3];
      }
#pragma unroll
      for (int ds = 0; ds < 2; ++ds) {
        const int rowV = ds * 32 + col;
        const bf16x8 vf = *(const bf16x8*)((const char*)Vtsh + rowV * 128 +
                                           (((kc2 << 1) | hi) ^ (rowV & 7)) * 16);
        oacc[ds] = __builtin_amdgcn_mfma_f32_32x32x16_bf16(pf.v, vf, oacc[ds], 0, 0, 0);
      }
    }
  }

  // ---- epilogue: store raw numerator + Z partial (no divide here)
  const float zrow = zacc + __shfl_xor(zacc, 32, 64);
  if (hi == 0)
    Zp[(size_t)split * Z_ELEMS + (size_t)(n0 + w * 32 + col) * NH + h] = zrow;

  float* onum = Onum + (size_t)split * ONUM_ELEMS;
#pragma unroll
  for (int ds = 0; ds < 2; ++ds) {
    const int d = ds * 32 + col;
#pragma unroll
    for (int r = 0; r < 16; ++r) {
      const int row = (r & 3) + 8 * (r >> 2) + 4 * hi;
      onum[((size_t)(n0 + w * 32 + row) * NH + h) * MD + d] = oacc[ds][r];
    }
  }
}

// ---------------- combine ----------------
__global__ __launch_bounds__(256) void diffattn_combine(
    const float* __restrict__ Onum, const float* __restrict__ Zp,
    float* __restrict__ Og, int nsplit) {
  const int idx = blockIdx.x * 256 + threadIdx.x;  // one float4 of output
  if (idx >= (int)(ONUM_ELEMS / 4)) return;
  const int nh = idx >> 4;
  const int d4 = (idx & 15) * 4;
  float z = 0.f;
  float4 o = make_float4(0.f, 0.f, 0.f, 0.f);
  for (int s = 0; s < nsplit; ++s) {
    z += Zp[(size_t)s * Z_ELEMS + nh];
    const float4 t = *(const float4*)(Onum + (size_t)s * ONUM_ELEMS +
                                      (size_t)nh * MD + d4);
    o.x += t.x; o.y += t.y; o.z += t.z; o.w += t.w;
  }
  const float zi = __builtin_amdgcn_rcpf(z);
  float4 r = make_float4(o.x * zi, o.y * zi, o.z * zi, o.w * zi);
  *(float4*)(Og + (size_t)nh * MD + d4) = r;
}

extern "C" void kernel_launch(void* const* d_in, const int* in_sizes, int n_in,
                              void* d_out, int out_size, void* d_ws, size_t ws_size,
                              hipStream_t stream) {
  const float* Q = (const float*)d_in[0];
  const float* K = (const float*)d_in[1];
  const float* V = (const float*)d_in[2];
  float* O = (float*)d_out;

  const size_t conv_bytes = (KB_ELEMS + VTB_ELEMS) * sizeof(unsigned short);
  int nsplit = 4;
  while (nsplit > 1 &&
         (size_t)nsplit * (ONUM_ELEMS + Z_ELEMS) * sizeof(float) + conv_bytes >
             ws_size)
    nsplit >>= 1;

  float* Onum = (float*)d_ws;
  float* Zp   = Onum + (size_t)nsplit * ONUM_ELEMS;
  unsigned short* Kbb = (unsigned short*)(Zp + (size_t)nsplit * Z_ELEMS);
  unsigned short* Vtb = Kbb + KB_ELEMS;

  const int lLen = NL / nsplit;
  diffattn_prepass<<<dim3(8 * (NL / 64)), dim3(256), 0, stream>>>(K, V, Kbb, Vtb);
  diffattn_partial<<<dim3(8 * 32 * nsplit), dim3(256), 0, stream>>>(
      Q, Kbb, Vtb, Onum, Zp, nsplit, lLen);
  diffattn_combine<<<dim3((ONUM_ELEMS / 4 + 255) / 256), dim3(256), 0, stream>>>(
      Onum, Zp, O, nsplit);
}